// Round 6
// baseline (18991.504 us; speedup 1.0000x reference)
//
#include <hip/hip_runtime.h>
#include <hip/hip_bf16.h>
#include <cstddef>
#include <type_traits>

typedef unsigned int u32;
typedef short bf16x8 __attribute__((ext_vector_type(8)));
typedef float f32x4 __attribute__((ext_vector_type(4)));
typedef _Float16 hf2 __attribute__((ext_vector_type(2)));

#define TC 256          // time-chunk length
#define NCHUNK 8        // 2048 / TC

// ---------- helpers ----------
__device__ __forceinline__ float sigf(float x) {
    return __builtin_amdgcn_rcpf(1.f + __expf(-x));
}
__device__ __forceinline__ float tanhf_fast(float x) {
    return 1.f - 2.f * __builtin_amdgcn_rcpf(1.f + __expf(2.f * x));
}
__device__ __forceinline__ float fdot2u(u32 a, u32 b, float acc) {
#if __has_builtin(__builtin_amdgcn_fdot2)
    return __builtin_amdgcn_fdot2(__builtin_bit_cast(hf2, a),
                                  __builtin_bit_cast(hf2, b), acc, false);
#else
    hf2 av = __builtin_bit_cast(hf2, a), bv = __builtin_bit_cast(hf2, b);
    return fmaf((float)av.y, (float)bv.y, fmaf((float)av.x, (float)bv.x, acc));
#endif
}
__device__ __forceinline__ u32 packh2(float a, float b) {
    hf2 p; p.x = (_Float16)a; p.y = (_Float16)b;
    return __builtin_bit_cast(u32, p);
}
__device__ __forceinline__ float loh(u32 p) { return (float)__builtin_bit_cast(hf2, p).x; }
__device__ __forceinline__ float hih(u32 p) { return (float)__builtin_bit_cast(hf2, p).y; }

// ---------- dtype sniff: bf16 (1) vs fp32 (0) ----------
__global__ void sniff(const u32* __restrict__ src, int nwords, int* __restrict__ flag) {
    __shared__ int cnt[256];
    int tid = threadIdx.x;
    size_t idx = (size_t)tid * (size_t)nwords / 256;
    u32 u = src[idx];
    int e = (u >> 7) & 0xFF;
    cnt[tid] = (e >= 100 && e <= 140) ? 1 : 0;
    __syncthreads();
    for (int s = 128; s > 0; s >>= 1) {
        if (tid < s) cnt[tid] += cnt[tid + s];
        __syncthreads();
    }
    if (tid == 0) *flag = (cnt[0] >= 144) ? 1 : 0;
}

// ---------- generic convert -> bf16 ----------
__global__ void conv_any(const void* __restrict__ src, __hip_bfloat16* __restrict__ dst,
                         int n, const int* __restrict__ flag) {
    int i = blockIdx.x * 256 + threadIdx.x;
    if (i >= n) return;
    if (*flag)
        dst[i] = ((const __hip_bfloat16*)src)[i];
    else
        dst[i] = __float2bfloat16(((const float*)src)[i]);
}

// ---------- per-chunk X convert ----------
__global__ void conv_x(const void* __restrict__ X, __hip_bfloat16* __restrict__ dst,
                       int tc, const int* __restrict__ flag) {
    int i = blockIdx.x * 256 + threadIdx.x;     // 2097152 total
    int b = i >> 15, rem = i & 32767, ti = rem >> 7, d = rem & 127;
    size_t s = ((size_t)(b * 2048 + tc * TC + ti) << 7) | d;
    float v = (*flag) ? __bfloat162float(((const __hip_bfloat16*)X)[s])
                      : ((const float*)X)[s];
    dst[i] = __float2bfloat16(v);
}

// ---------- pack Wh [256][1024] -> fp16 k-pair packed [128][1024] ----------
__global__ void pack_wh(const void* __restrict__ Wh, u32* __restrict__ Whp,
                        const int* __restrict__ flag) {
    int i = blockIdx.x * 256 + threadIdx.x;   // 131072 total
    int k2 = i >> 10, n = i & 1023;
    float w0, w1;
    if (*flag) {
        w0 = __bfloat162float(((const __hip_bfloat16*)Wh)[(k2 * 2) * 1024 + n]);
        w1 = __bfloat162float(((const __hip_bfloat16*)Wh)[(k2 * 2 + 1) * 1024 + n]);
    } else {
        w0 = ((const float*)Wh)[(k2 * 2) * 1024 + n];
        w1 = ((const float*)Wh)[(k2 * 2 + 1) * 1024 + n];
    }
    Whp[i] = packh2(w0, w1);
}

// ---------- GEMM (unchanged, proven) ----------
template <typename OutT>
__global__ void gemm_bias(const __hip_bfloat16* __restrict__ A,
                          const __hip_bfloat16* __restrict__ B,
                          const __hip_bfloat16* __restrict__ bias,
                          OutT* __restrict__ C, int N, int K,
                          long strideA, long strideC) {
    __shared__ short As[64 * 72];
    __shared__ short Bs[64 * 72];
    const int tid = threadIdx.x;
    const int n0 = blockIdx.x * 64;
    const int m0 = blockIdx.y * 64;
    const int w = tid >> 6, lane = tid & 63;
    const int lm = lane & 15, lq = lane >> 4;

    f32x4 acc[4];
#pragma unroll
    for (int i = 0; i < 4; ++i) acc[i] = (f32x4){0.f, 0.f, 0.f, 0.f};

    const int kchunks = K >> 6;
    for (int kc = 0; kc < kchunks; ++kc) {
#pragma unroll
        for (int p = 0; p < 2; ++p) {
            int m = m0 + (tid >> 3) + 32 * p;
            int ch = tid & 7;
            size_t aoff = ((size_t)(m >> 8) * strideA + (m & 255)) * K;
            uint4 v = *(const uint4*)(A + aoff + kc * 64 + ch * 8);
            *(uint4*)(As + ((tid >> 3) + 32 * p) * 72 + ch * 8) = v;
        }
#pragma unroll
        for (int p = 0; p < 2; ++p) {
            int k  = (tid >> 3) + 32 * p;
            int ne = (tid & 7) * 8;
            uint4 v = *(const uint4*)(B + (size_t)(kc * 64 + k) * N + n0 + ne);
            const short* sv = (const short*)&v;
#pragma unroll
            for (int e = 0; e < 8; ++e) Bs[(ne + e) * 72 + k] = sv[e];
        }
        __syncthreads();
#pragma unroll
        for (int ks = 0; ks < 2; ++ks) {
            bf16x8 af = *(const bf16x8*)(As + (16 * w + lm) * 72 + ks * 32 + lq * 8);
#pragma unroll
            for (int nt = 0; nt < 4; ++nt) {
                bf16x8 bfr = *(const bf16x8*)(Bs + (nt * 16 + lm) * 72 + ks * 32 + lq * 8);
                acc[nt] = __builtin_amdgcn_mfma_f32_16x16x32_bf16(af, bfr, acc[nt], 0, 0, 0);
            }
        }
        __syncthreads();
    }
#pragma unroll
    for (int nt = 0; nt < 4; ++nt) {
        int col = n0 + nt * 16 + lm;
        float bv = __bfloat162float(bias[col]);
#pragma unroll
        for (int r = 0; r < 4; ++r) {
            int mrow = m0 + 16 * w + lq * 4 + r;
            size_t coff = ((size_t)(mrow >> 8) * strideC + (mrow & 255)) * N;
            float v = acc[nt][r] + bv;
            if constexpr (std::is_same_v<OutT, _Float16>)
                C[coff + col] = (_Float16)v;
            else if constexpr (std::is_same_v<OutT, float>)
                C[coff + col] = v;
            else
                C[coff + col] = __float2bfloat16(v);
        }
    }
}

// ---------- LSTM recurrence: 64 WGs x 512 threads, thread t owns cols 2t,2t+1 ----------
// Wh row split: rows 0..71 in VGPRs (uint2[72]); rows 72..83 in LDS (48 KB);
// rows 84..103 streamed phase A; rows 104..127 streamed phase B.
#define RREG 72
#define RLDS 12
#define RSA  20
#define RSB  24

__global__ __launch_bounds__(512, 2) void lstm_rec_chunk(
        const u32* __restrict__ xg32,     // [64][TC][512] fp16-pairs
        const uint2* __restrict__ Whp2,   // [128][512] uint2 (two adjacent cols)
        u32* __restrict__ hs32,           // [64][TC][128] bf16-pairs
        u32* __restrict__ hstate,         // [64][128] fp16-pairs
        float2* __restrict__ cstate2,     // [64][128]
        int first) {
    const int t = threadIdx.x;            // 0..511
    const int b = blockIdx.x;
    __shared__ uint2 wlds2[RLDS * 512];             // 48 KB
    __shared__ u32 garr32[512];                     // 2 KB (fp16 gate pairs)
    __shared__ __align__(16) u32 hbuf[128];         // 512 B (h fp16 pairs)

    // --- weight residency setup ---
    uint2 wr[RREG];
#pragma unroll
    for (int r = 0; r < RREG; ++r) wr[r] = Whp2[r * 512 + t];
#pragma unroll
    for (int r = 0; r < RLDS; ++r) wlds2[r * 512 + t] = Whp2[(RREG + r) * 512 + t];

    float c0 = 0.f, c1 = 0.f;
    if (t < 128) {
        hbuf[t] = first ? packh2(0.f, 0.f) : hstate[b * 128 + t];
        if (!first) { float2 cc = cstate2[b * 128 + t]; c0 = cc.x; c1 = cc.y; }
    }
    __syncthreads();

    const uint2* strA = Whp2 + (RREG + RLDS) * 512 + t;          // rows 84..103
    const uint2* strB = Whp2 + (RREG + RLDS + RSA) * 512 + t;    // rows 104..127
    const u32* xgp = xg32 + (size_t)b * TC * 512 + t;
    u32* hsp = hs32 + (size_t)b * TC * 128;
    const uint4* hb4 = (const uint4*)hbuf;

    u32 xg_cur = xgp[0];

    for (int ts = 0; ts < TC; ++ts) {
        // issue stream-A loads for this step
        uint2 sa[RSA];
#pragma unroll
        for (int r = 0; r < RSA; ++r) sa[r] = strA[(size_t)r * 512];

        float acc0 = loh(xg_cur);
        float acc1 = hih(xg_cur);

        // --- register rows 0..71 (18 groups) ---
#pragma unroll
        for (int g = 0; g < 18; ++g) {
            uint4 h4 = hb4[g];
            acc0 = fdot2u(wr[4 * g + 0].x, h4.x, acc0); acc1 = fdot2u(wr[4 * g + 0].y, h4.x, acc1);
            acc0 = fdot2u(wr[4 * g + 1].x, h4.y, acc0); acc1 = fdot2u(wr[4 * g + 1].y, h4.y, acc1);
            acc0 = fdot2u(wr[4 * g + 2].x, h4.z, acc0); acc1 = fdot2u(wr[4 * g + 2].y, h4.z, acc1);
            acc0 = fdot2u(wr[4 * g + 3].x, h4.w, acc0); acc1 = fdot2u(wr[4 * g + 3].y, h4.w, acc1);
        }
        // --- LDS rows 72..83 (3 groups) ---
#pragma unroll
        for (int g = 0; g < 3; ++g) {
            uint4 h4 = hb4[18 + g];
#pragma unroll
            for (int j = 0; j < 4; ++j) {
                uint2 wv = wlds2[(4 * g + j) * 512 + t];
                u32 hp = (j == 0) ? h4.x : (j == 1) ? h4.y : (j == 2) ? h4.z : h4.w;
                acc0 = fdot2u(wv.x, hp, acc0);
                acc1 = fdot2u(wv.y, hp, acc1);
            }
        }
        // --- stream A part 1: groups 21..23 (rows 84..95) ---
#pragma unroll
        for (int g = 0; g < 3; ++g) {
            uint4 h4 = hb4[21 + g];
#pragma unroll
            for (int j = 0; j < 4; ++j) {
                uint2 wv = sa[4 * g + j];
                u32 hp = (j == 0) ? h4.x : (j == 1) ? h4.y : (j == 2) ? h4.z : h4.w;
                acc0 = fdot2u(wv.x, hp, acc0);
                acc1 = fdot2u(wv.y, hp, acc1);
            }
        }
        // issue stream-B loads
        uint2 sb[RSB];
#pragma unroll
        for (int r = 0; r < RSB; ++r) sb[r] = strB[(size_t)r * 512];
        // --- stream A part 2: groups 24..25 (rows 96..103) ---
#pragma unroll
        for (int g = 3; g < 5; ++g) {
            uint4 h4 = hb4[21 + g];
#pragma unroll
            for (int j = 0; j < 4; ++j) {
                uint2 wv = sa[4 * g + j];
                u32 hp = (j == 0) ? h4.x : (j == 1) ? h4.y : (j == 2) ? h4.z : h4.w;
                acc0 = fdot2u(wv.x, hp, acc0);
                acc1 = fdot2u(wv.y, hp, acc1);
            }
        }
        // --- stream B: groups 26..31 (rows 104..127) ---
#pragma unroll
        for (int g = 0; g < 6; ++g) {
            uint4 h4 = hb4[26 + g];
#pragma unroll
            for (int j = 0; j < 4; ++j) {
                uint2 wv = sb[4 * g + j];
                u32 hp = (j == 0) ? h4.x : (j == 1) ? h4.y : (j == 2) ? h4.z : h4.w;
                acc0 = fdot2u(wv.x, hp, acc0);
                acc1 = fdot2u(wv.y, hp, acc1);
            }
        }

        // prefetch next xg
        if (ts + 1 < TC) xg_cur = xgp[(size_t)(ts + 1) * 512];

        // activations: cols [0,768) sigmoid, [768,1024) tanh; pairs never cross
        float s0, s1;
        if (t < 384) { s0 = sigf(acc0); s1 = sigf(acc1); }
        else         { s0 = tanhf_fast(acc0); s1 = tanhf_fast(acc1); }
        garr32[t] = packh2(s0, s1);
        __syncthreads();

        if (t < 128) {
            u32 fp = garr32[t];
            u32 ip = garr32[t + 128];
            u32 op = garr32[t + 256];
            u32 cp = garr32[t + 384];
            c0 = c0 * loh(fp) + loh(cp) * loh(ip);
            c1 = c1 * hih(fp) + hih(cp) * hih(ip);
            float h0 = loh(op) * tanhf_fast(c0);
            float h1 = hih(op) * tanhf_fast(c1);
            hbuf[t] = packh2(h0, h1);
            unsigned short b0 = __builtin_bit_cast(unsigned short, __float2bfloat16(h0));
            unsigned short b1 = __builtin_bit_cast(unsigned short, __float2bfloat16(h1));
            hsp[(size_t)ts * 128 + t] = (u32)b0 | ((u32)b1 << 16);
        }
        __syncthreads();
    }

    if (t < 128) {
        hstate[b * 128 + t] = hbuf[t];
        float2 cc; cc.x = c0; cc.y = c1;
        cstate2[b * 128 + t] = cc;
    }
}

// ---------- launch ----------
extern "C" void kernel_launch(void* const* d_in, const int* in_sizes, int n_in,
                              void* d_out, int out_size, void* d_ws, size_t ws_size,
                              hipStream_t stream) {
    const void* X    = d_in[0];  // [64,2048,128] fp32 (sniffed)
    const void* Wx   = d_in[1];
    const void* Wh   = d_in[2];
    const void* bg   = d_in[3];
    const void* Wout = d_in[4];
    const void* bout = d_in[5];
    float* out = (float*)d_out;  // [64,2048,128] fp32

    // workspace layout (~47.2 MB)
    char* ws = (char*)d_ws;
    _Float16* xg_c        = (_Float16*)(ws + 0);                 // 33554432
    __hip_bfloat16* Xc_b  = (__hip_bfloat16*)(ws + 33554432);    //  4194304
    __hip_bfloat16* hs_c  = (__hip_bfloat16*)(ws + 37748736);    //  8388608
    u32* Whp              = (u32*)(ws + 46137344);               //   524288
    __hip_bfloat16* Wxb   = (__hip_bfloat16*)(ws + 46661632);    //   262144
    __hip_bfloat16* Woutb = (__hip_bfloat16*)(ws + 46923776);    //    65536
    __hip_bfloat16* bgb   = (__hip_bfloat16*)(ws + 46989312);    //     2048
    __hip_bfloat16* boutb = (__hip_bfloat16*)(ws + 46991360);    //      512
    u32* hstate           = (u32*)(ws + 46991872);               //    32768
    float2* cstate2       = (float2*)(ws + 47024640);            //    65536
    int* flags            = (int*)(ws + 47122944);               //       64

    for (int i = 0; i < 6; ++i)
        sniff<<<dim3(1), dim3(256), 0, stream>>>((const u32*)d_in[i],
                                                 in_sizes[i] / 2, flags + i);
    conv_any<<<dim3(512), dim3(256), 0, stream>>>(Wx, Wxb, 131072, flags + 1);
    conv_any<<<dim3(128), dim3(256), 0, stream>>>(Wout, Woutb, 32768, flags + 4);
    conv_any<<<dim3(4),   dim3(256), 0, stream>>>(bg, bgb, 1024, flags + 3);
    conv_any<<<dim3(1),   dim3(256), 0, stream>>>(bout, boutb, 128, flags + 5);
    pack_wh<<<dim3(512), dim3(256), 0, stream>>>(Wh, Whp, flags + 2);

    for (int tc = 0; tc < NCHUNK; ++tc) {
        conv_x<<<dim3(8192), dim3(256), 0, stream>>>(X, Xc_b, tc, flags + 0);
        gemm_bias<_Float16><<<dim3(16, 256), dim3(256), 0, stream>>>(
            Xc_b, Wxb, bgb, xg_c, 1024, 128, 256L, 256L);
        lstm_rec_chunk<<<dim3(64), dim3(512), 0, stream>>>(
            (const u32*)xg_c, (const uint2*)Whp, (u32*)hs_c,
            hstate, cstate2, tc == 0 ? 1 : 0);
        float* outc = out + (size_t)tc * TC * 128;
        gemm_bias<float><<<dim3(2, 256), dim3(256), 0, stream>>>(
            hs_c, Woutb, boutb, outc, 128, 256, 256L, 2048L);
    }
}